// Round 7
// baseline (369.710 us; speedup 1.0000x reference)
//
#include <hip/hip_runtime.h>
#include <hip/hip_fp16.h>

// VectorQuantizer — round 14: code-split k_main, SPILL-FIXED.
// r13 post-mortem: WRITE_SIZE 100 MB = scratch spill at launch_bounds(256,4)
// (unified-file need ~140 > 128 budget; frags live in AGPRs, which is why
// r10/r11 showed VGPR=60 with no remat — the r11 pin was correctly a no-op).
// Fix: (1) ni-blocked sub-passes -> acc[2][2] (-16 regs, need ~124);
// (2) launch_bounds(256,3) -> 170-reg budget, no spill possible; if actual
// usage <=128 HW still gets 4 blk/CU (LDS 34 KB allows), else 3 + mild tail.
// Geometry: 1024 blocks = 2 code-halves x 512 px-stripes; wave = 32 px
// (mi=2, each ds_read_b128 feeds 4 MFMA -> LDS floor 20.5us; MFMA 33us).
// k_merge combines halves with exact sequential tie-break + builds recheck
// list. Arithmetic unchanged (A-side fp16 hi+lo, TAU=0.075).
// 6 dispatches: prep, main, merge, recheck, epi, final.

#define C_DIM   256
#define K_CODES 1024
#define HW      4096
#define N_OUT   (16 * C_DIM * HW)
#define TAU     0.075f
#define LISTCAP 65536
#define RPP     8
#define RGRID   512

typedef _Float16 f16x8 __attribute__((ext_vector_type(8)));
typedef float    f32x4 __attribute__((ext_vector_type(4)));
typedef unsigned u32x4 __attribute__((ext_vector_type(4)));

__device__ __forceinline__ void gld16(const void* g, void* lds) {
#if __has_builtin(__builtin_amdgcn_global_load_lds)
  __builtin_amdgcn_global_load_lds(
      (const __attribute__((address_space(1))) unsigned int*)g,
      (__attribute__((address_space(3))) unsigned int*)lds, 16, 0, 0);
#else
  ((int4*)lds)[threadIdx.x & 63] = *(const int4*)g;
#endif
}

// ---- fused prep: blocks 0-127 pack Bp; 128-383 e2; 384 zeros loss+cnt -----
// Bp slot s: l=s&63, ks=(s>>6)&7, ni=(s>>9)&7, cb=s>>12  (8 cb x 128 codes)
// code n = cb*128 + ni*16 + (l&15); c0 = ks*32 + (l>>4)*8; 4 dw = 8 consec. c
__global__ __launch_bounds__(256) void k_prep(const float* __restrict__ emb,
                                              float* __restrict__ e2,
                                              unsigned* __restrict__ Bp,
                                              float* __restrict__ lossp,
                                              int* __restrict__ cntp) {
  const int blk = blockIdx.x, t = threadIdx.x;
  if (blk < 128) {
    const int s = blk * 256 + t;
    const int l = s & 63, ks = (s >> 6) & 7, ni = (s >> 9) & 7, cb = s >> 12;
    const int n = (cb << 7) + (ni << 4) + (l & 15);
    const int c0 = (ks << 5) + ((l >> 4) << 3);
    const float* er = emb + (size_t)n * C_DIM + c0;
    u32x4 out;
#pragma unroll
    for (int d = 0; d < 4; ++d) {
      __half2 h = __floats2half2_rn(er[2 * d], er[2 * d + 1]);
      out[d] = *(unsigned*)&h;
    }
    *(u32x4*)(Bp + (size_t)s * 4) = out;
  } else if (blk < 384) {
    const int w = t >> 6, l = t & 63;
    const int k = (blk - 128) * 4 + w;
    const float4 v = *(const float4*)(emb + (size_t)k * C_DIM + l * 4);
    float s = v.x * v.x + v.y * v.y + v.z * v.z + v.w * v.w;
    for (int m = 32; m; m >>= 1) s += __shfl_down(s, m, 64);
    if (l == 0) e2[k] = s;
  } else if (t == 0) {
    *lossp = 0.f; *cntp = 0;
  }
}

// ---- main: 1024 blocks = 2 code-halves x 512 px-stripes; 2mi, ni-blocked --
__global__ __launch_bounds__(256, 3) void k_main(
    const float* __restrict__ x, const unsigned* __restrict__ Bp,
    const float* __restrict__ e2g, float* __restrict__ d1o,
    float* __restrict__ d2o, int* __restrict__ i1o) {
  __shared__ unsigned Bs[32 * 256];   // 32 KB: 64 codes/pass
  __shared__ float e2s[512];          // 2 KB   (total 34 KB)

  const int t = threadIdx.x;
  const int wv = t >> 6, l = t & 63;
  const int l15 = l & 15, l4 = l >> 4;
  const int blk = blockIdx.x;         // 1024 = 2 halves * (16 b * 32 stripes)
  const int h = blk >> 9;             // code half 0/1
  const int s = blk & 511;
  const int b = s >> 5;
  const int p0 = (s & 31) << 7;       // 128-px stripe
  const int pxw = p0 + (wv << 5);     // wave's 32-px base (2 mi)
  const float* xb = x + ((size_t)b << 20);

  e2s[t] = e2g[(h << 9) + t];
  e2s[t + 256] = e2g[(h << 9) + 256 + t];

  // A fragments: 2 mi x 8 ks, hi + residual-lo, converted once (AGPR-resident)
  u32x4 afu[2][8];
  u32x4 afl[2][8];
#pragma unroll
  for (int mi = 0; mi < 2; ++mi) {
    const int px = pxw + (mi << 4) + l15;
#pragma unroll
    for (int ks = 0; ks < 8; ++ks) {
#pragma unroll
      for (int d = 0; d < 4; ++d) {
        const int c = (ks << 5) + (l4 << 3) + (d << 1);
        const float v0 = xb[((size_t)c << 12) + px];
        const float v1 = xb[((size_t)(c + 1) << 12) + px];
        __half2 hh = __floats2half2_rn(v0, v1);
        afu[mi][ks][d] = *(unsigned*)&hh;
        __half2 hl = __floats2half2_rn(v0 - __low2float(hh), v1 - __high2float(hh));
        afl[mi][ks][d] = *(unsigned*)&hl;
      }
    }
  }

  float d1[2][4], d2v[2][4];
  int   i1[2][4];
#pragma unroll
  for (int mi = 0; mi < 2; ++mi)
#pragma unroll
    for (int r = 0; r < 4; ++r) { d1[mi][r] = 1e30f; d2v[mi][r] = 1e30f; i1[mi][r] = 0; }

  for (int p = 0; p < 8; ++p) {       // 8 passes x 64 codes = this half's 512
    __syncthreads();                  // prev-pass consumers done
    const unsigned* src =
        Bp + ((size_t)((h << 2) + (p >> 1)) << 14) + ((size_t)(p & 1) << 13);
#pragma unroll
    for (int i = 0; i < 8; ++i) {
      const int lt = (wv << 3) + i;   // local tile = ni*8+ks in [0,32)
      gld16(src + (lt << 8) + (l << 2), (void*)&Bs[lt << 8]);
    }
    __syncthreads();                  // staged data visible

    const int p64 = p << 6;
    // ni-blocked: 2 sub-passes x 2 ni -> acc[2][2] (16 regs, spill-safe)
#pragma unroll
    for (int nb = 0; nb < 2; ++nb) {
      f32x4 acc[2][2];
#pragma unroll
      for (int mi = 0; mi < 2; ++mi)
#pragma unroll
        for (int nj = 0; nj < 2; ++nj) acc[mi][nj] = (f32x4){0.f, 0.f, 0.f, 0.f};

#pragma unroll
      for (int ks = 0; ks < 8; ++ks) {
        const f16x8 a0h = __builtin_bit_cast(f16x8, afu[0][ks]);
        const f16x8 a0l = __builtin_bit_cast(f16x8, afl[0][ks]);
        const f16x8 a1h = __builtin_bit_cast(f16x8, afu[1][ks]);
        const f16x8 a1l = __builtin_bit_cast(f16x8, afl[1][ks]);
#pragma unroll
        for (int nj = 0; nj < 2; ++nj) {
          const int ni = (nb << 1) + nj;
          // ONE ds_read_b128 feeds FOUR MFMA (2 mi x hi/lo)
          const f16x8 bf = __builtin_bit_cast(
              f16x8, *(const u32x4*)&Bs[(((ni << 3) + ks) << 8) + (l << 2)]);
          acc[0][nj] = __builtin_amdgcn_mfma_f32_16x16x32_f16(a0h, bf, acc[0][nj], 0, 0, 0);
          acc[1][nj] = __builtin_amdgcn_mfma_f32_16x16x32_f16(a1h, bf, acc[1][nj], 0, 0, 0);
          acc[0][nj] = __builtin_amdgcn_mfma_f32_16x16x32_f16(a0l, bf, acc[0][nj], 0, 0, 0);
          acc[1][nj] = __builtin_amdgcn_mfma_f32_16x16x32_f16(a1l, bf, acc[1][nj], 0, 0, 0);
        }
      }

      // register top-2 update over this half's local code ids [0,512)
#pragma unroll
      for (int nj = 0; nj < 2; ++nj) {
        const int   c   = p64 + (((nb << 1) + nj) << 4) + l15;
        const float e2v = e2s[c];
#pragma unroll
        for (int mi = 0; mi < 2; ++mi)
#pragma unroll
          for (int r = 0; r < 4; ++r) {
            const float sc = fmaf(-2.f, acc[mi][nj][r], e2v);
            const bool lt = sc < d1[mi][r];
            d2v[mi][r] = lt ? d1[mi][r] : (sc < d2v[mi][r] ? sc : d2v[mi][r]);
            i1[mi][r]  = lt ? c : i1[mi][r];
            d1[mi][r]  = lt ? sc : d1[mi][r];
          }
      }
    }
  }

  // cross-lane merge (16 lanes share a pixel row); write half-results
#pragma unroll
  for (int mi = 0; mi < 2; ++mi) {
#pragma unroll
    for (int r = 0; r < 4; ++r) {
      float pd1 = d1[mi][r], pd2 = d2v[mi][r];
      int   pi1 = i1[mi][r];
#pragma unroll
      for (int m = 1; m < 16; m <<= 1) {
        const float od1 = __shfl_xor(pd1, m);
        const float od2 = __shfl_xor(pd2, m);
        const int   oi1 = __shfl_xor(pi1, m);
        const bool take = (od1 < pd1) || (od1 == pd1 && oi1 < pi1);
        const float loser = take ? pd1 : od1;
        pd2 = fminf(fminf(pd2, od2), loser);
        pd1 = take ? od1 : pd1;
        pi1 = take ? oi1 : pi1;
      }
      if (l15 == 0) {
        const int px = pxw + (mi << 4) + (l4 << 2) + r;
        const int gp = (b << 12) + px;
        const int off = (h << 16) + gp;
        d1o[off] = pd1;
        d2o[off] = pd2;
        i1o[off] = (h << 9) + pi1;    // global code index
      }
    }
  }
}

// ---- merge: per-px top-2 across the two code halves; flag near-ties -------
__global__ __launch_bounds__(256) void k_merge(
    const float* __restrict__ d1o, const float* __restrict__ d2o,
    const int* __restrict__ i1o, int* __restrict__ idxw,
    int* __restrict__ list, int* __restrict__ cntp) {
  const int px = blockIdx.x * 256 + threadIdx.x;   // 256 blocks
  const float a1 = d1o[px], a2 = d2o[px];
  const int   ai = i1o[px];
  const float b1 = d1o[65536 + px], b2 = d2o[65536 + px];
  const int   bi = i1o[65536 + px];
  // exact sequential tie-break: lower index wins on equal d1 (ai < bi always)
  const bool take_a = (a1 < b1) || (a1 == b1 && ai < bi);
  const float d1 = take_a ? a1 : b1;
  const int   i1 = take_a ? ai : bi;
  const float loser = take_a ? b1 : a1;
  const float d2 = fminf(fminf(a2, b2), loser);
  idxw[px] = i1;
  if (d2 - d1 < TAU) {
    const int pos = atomicAdd(cntp, 1);
    if (pos < LISTCAP) list[pos] = px;
  }
}

// ---- exact fp32 recheck: 8 flagged pixels per block share codebook sweep --
__global__ __launch_bounds__(256) void k_recheck(
    const float* __restrict__ x, const float* __restrict__ emb,
    const float* __restrict__ e2, const int* __restrict__ list,
    const int* __restrict__ cntp, int* __restrict__ idxw) {
  __shared__ float xs[RPP][C_DIM];
  __shared__ int   gps[RPP];
  __shared__ float wbest[RPP][4];
  __shared__ int   wbidx[RPP][4];
  const int t = threadIdx.x;
  const int cnt = min(*cntp, LISTCAP);
  float e2l[4];
#pragma unroll
  for (int j = 0; j < 4; ++j) e2l[j] = e2[t * 4 + j];

  for (int base = blockIdx.x * RPP; base < cnt; base += RGRID * RPP) {
    __syncthreads();
    if (t < RPP) gps[t] = (base + t < cnt) ? list[base + t] : -1;
    __syncthreads();
#pragma unroll
    for (int s = 0; s < RPP; ++s) {
      const int gp = gps[s];
      if (gp >= 0)
        xs[s][t] = x[((size_t)(gp >> 12) << 20) + ((size_t)t << 12) + (gp & 4095)];
    }
    __syncthreads();

    float acc[4][RPP];
#pragma unroll
    for (int j = 0; j < 4; ++j)
#pragma unroll
      for (int s = 0; s < RPP; ++s) acc[j][s] = 0.f;

    const float* er = emb + (size_t)(t * 4) * C_DIM;
    for (int c = 0; c < C_DIM; c += 4) {
      const float4 e0 = *(const float4*)(er + c);
      const float4 e1 = *(const float4*)(er + C_DIM + c);
      const float4 e2r = *(const float4*)(er + 2 * C_DIM + c);
      const float4 e3 = *(const float4*)(er + 3 * C_DIM + c);
#pragma unroll
      for (int s = 0; s < RPP; ++s) {
        const float4 xv = *(const float4*)&xs[s][c];
        acc[0][s] = fmaf(e0.x, xv.x, acc[0][s]); acc[0][s] = fmaf(e0.y, xv.y, acc[0][s]);
        acc[0][s] = fmaf(e0.z, xv.z, acc[0][s]); acc[0][s] = fmaf(e0.w, xv.w, acc[0][s]);
        acc[1][s] = fmaf(e1.x, xv.x, acc[1][s]); acc[1][s] = fmaf(e1.y, xv.y, acc[1][s]);
        acc[1][s] = fmaf(e1.z, xv.z, acc[1][s]); acc[1][s] = fmaf(e1.w, xv.w, acc[1][s]);
        acc[2][s] = fmaf(e2r.x, xv.x, acc[2][s]); acc[2][s] = fmaf(e2r.y, xv.y, acc[2][s]);
        acc[2][s] = fmaf(e2r.z, xv.z, acc[2][s]); acc[2][s] = fmaf(e2r.w, xv.w, acc[2][s]);
        acc[3][s] = fmaf(e3.x, xv.x, acc[3][s]); acc[3][s] = fmaf(e3.y, xv.y, acc[3][s]);
        acc[3][s] = fmaf(e3.z, xv.z, acc[3][s]); acc[3][s] = fmaf(e3.w, xv.w, acc[3][s]);
      }
    }

    for (int s = 0; s < RPP; ++s) {
      float bd = 1e30f;
      int   bk = 0;
#pragma unroll
      for (int j = 0; j < 4; ++j) {
        const float sc = fmaf(-2.f, acc[j][s], e2l[j]);
        if (sc < bd) { bd = sc; bk = t * 4 + j; }   // ascending j => first idx
      }
#pragma unroll
      for (int m = 1; m < 64; m <<= 1) {
        const float od = __shfl_xor(bd, m);
        const int   oi = __shfl_xor(bk, m);
        if (od < bd || (od == bd && oi < bk)) { bd = od; bk = oi; }
      }
      if ((t & 63) == 0) { wbest[s][t >> 6] = bd; wbidx[s][t >> 6] = bk; }
    }
    __syncthreads();
    if (t < RPP && gps[t] >= 0) {
      float bd = wbest[t][0];
      int   bk = wbidx[t][0];
      for (int wv = 1; wv < 4; ++wv)
        if (wbest[t][wv] < bd || (wbest[t][wv] == bd && wbidx[t][wv] < bk)) {
          bd = wbest[t][wv]; bk = wbidx[t][wv];
        }
      idxw[gps[t]] = bk;
    }
  }
}

// ---- epilogue: gather + transposed store + loss (r1/r3-validated) ---------
__global__ __launch_bounds__(256) void k_epi(const float* __restrict__ x,
                                             const float* __restrict__ emb,
                                             const int* __restrict__ idxw,
                                             float* __restrict__ out,
                                             float* __restrict__ loss_acc) {
  __shared__ int bidx_s[64];
  __shared__ float lred[4];
  const int t = threadIdx.x;
  const int tile = blockIdx.x;     // 1024 = 16 b * 64
  const int b = tile >> 6, p0 = (tile & 63) << 6;
  const float* xb = x + ((size_t)b << 20) + p0;
  float* outb = out + ((size_t)b << 20) + p0;
  if (t < 64) bidx_s[t] = idxw[((size_t)b << 12) + p0 + t] & 1023;
  __syncthreads();
  float lsum = 0.f;
#pragma unroll 4
  for (int i = 0; i < 16; ++i) {
    const int fidx = t + 256 * i;
    const int c = fidx >> 4, p4 = (fidx & 15) << 2;
    const float4 x4 = *(const float4*)&xb[((size_t)c << 12) + p4];
    const int j0 = bidx_s[p4], j1 = bidx_s[p4 + 1], j2 = bidx_s[p4 + 2], j3 = bidx_s[p4 + 3];
    const float q0 = emb[(size_t)j0 * C_DIM + c];
    const float q1 = emb[(size_t)j1 * C_DIM + c];
    const float q2 = emb[(size_t)j2 * C_DIM + c];
    const float q3 = emb[(size_t)j3 * C_DIM + c];
    const float d0 = q0 - x4.x, dd1 = q1 - x4.y, dd2 = q2 - x4.z, dd3 = q3 - x4.w;
    lsum += d0 * d0 + dd1 * dd1 + dd2 * dd2 + dd3 * dd3;
    float4 o; o.x = q0; o.y = q1; o.z = q2; o.w = q3;
    *(float4*)&outb[((size_t)c << 12) + p4] = o;
  }
  for (int off = 32; off > 0; off >>= 1) lsum += __shfl_down(lsum, off, 64);
  if ((t & 63) == 0) lred[t >> 6] = lsum;
  __syncthreads();
  if (t == 0) atomicAdd(loss_acc, lred[0] + lred[1] + lred[2] + lred[3]);
}

__global__ void k_final(const float* __restrict__ ws, float* __restrict__ out) {
  out[N_OUT] = 2.0f * ws[0] / (float)N_OUT;
}

// ================= round-1 fp32 fallback (tiny ws) ==========================
__global__ void k_zero(float* ws) { ws[0] = 0.f; }

__global__ __launch_bounds__(256) void k_e2f(const float* __restrict__ emb,
                                             float* __restrict__ e2) {
  int k = blockIdx.x * 256 + threadIdx.x;
  const float* e = emb + (size_t)k * C_DIM;
  float s = 0.f;
#pragma unroll 8
  for (int c = 0; c < C_DIM; ++c) s += e[c] * e[c];
  e2[k] = s;
}

__global__ __launch_bounds__(256, 4) void k_main_r1(
    const float* __restrict__ x, const float* __restrict__ emb,
    const float* __restrict__ e2, float* __restrict__ out,
    float* __restrict__ loss_acc) {
  __shared__ float smem[64 * 64 + 64 * 64];
  float* xs = smem;
  float* es = smem + 64 * 64;
  float* red_d = smem;
  int* red_i = (int*)(smem + 64 * 16);
  int* bidx_s = (int*)(smem + 64 * 32);
  float* lred = smem + 64 * 32 + 64;
  const int t = threadIdx.x;
  const int tile = blockIdx.x;
  const int b = tile >> 6;
  const int p0 = (tile & 63) << 6;
  const float* xb = x + (size_t)b * C_DIM * HW + p0;
  const int pg = t & 15, kg = t >> 4;
  float best0 = 1e30f, best1 = 1e30f, best2 = 1e30f, best3 = 1e30f;
  int bi0 = 0, bi1 = 0, bi2 = 0, bi3 = 0;
  for (int kc = 0; kc < 16; ++kc) {
    const int k0 = kc * 64;
    float a00 = 0, a01 = 0, a02 = 0, a03 = 0, a10 = 0, a11 = 0, a12 = 0, a13 = 0;
    float a20 = 0, a21 = 0, a22 = 0, a23 = 0, a30 = 0, a31 = 0, a32 = 0, a33 = 0;
    for (int cs0 = 0; cs0 < 4; ++cs0) {
      __syncthreads();
#pragma unroll
      for (int i = 0; i < 4; ++i) {
        int fidx = t + 256 * i;
        int cs = fidx >> 4, p4 = (fidx & 15) << 2;
        *(float4*)&xs[cs * 64 + p4] = *(const float4*)&xb[(size_t)(cs0 * 64 + cs) * HW + p4];
      }
      for (int i = 0; i < 16; ++i) {
        int idx2 = t + 256 * i;
        int cs = idx2 >> 6, kk = idx2 & 63;
        es[cs * 64 + kk] = emb[(size_t)(k0 + kk) * C_DIM + cs0 * 64 + cs];
      }
      __syncthreads();
#pragma unroll 8
      for (int cs = 0; cs < 64; ++cs) {
        const float4 xv = *(const float4*)&xs[cs * 64 + (pg << 2)];
        const float4 ev = *(const float4*)&es[cs * 64 + (kg << 2)];
        a00 += xv.x * ev.x; a01 += xv.x * ev.y; a02 += xv.x * ev.z; a03 += xv.x * ev.w;
        a10 += xv.y * ev.x; a11 += xv.y * ev.y; a12 += xv.y * ev.z; a13 += xv.y * ev.w;
        a20 += xv.z * ev.x; a21 += xv.z * ev.y; a22 += xv.z * ev.z; a23 += xv.z * ev.w;
        a30 += xv.w * ev.x; a31 += xv.w * ev.y; a32 += xv.w * ev.z; a33 += xv.w * ev.w;
      }
    }
    const int kb = k0 + (kg << 2);
    const float e20 = e2[kb], e21 = e2[kb + 1], e22 = e2[kb + 2], e23 = e2[kb + 3];
    float s;
    s = e20 - 2.f * a00; if (s < best0) { best0 = s; bi0 = kb; }
    s = e21 - 2.f * a01; if (s < best0) { best0 = s; bi0 = kb + 1; }
    s = e22 - 2.f * a02; if (s < best0) { best0 = s; bi0 = kb + 2; }
    s = e23 - 2.f * a03; if (s < best0) { best0 = s; bi0 = kb + 3; }
    s = e20 - 2.f * a10; if (s < best1) { best1 = s; bi1 = kb; }
    s = e21 - 2.f * a11; if (s < best1) { best1 = s; bi1 = kb + 1; }
    s = e22 - 2.f * a12; if (s < best1) { best1 = s; bi1 = kb + 2; }
    s = e23 - 2.f * a13; if (s < best1) { best1 = s; bi1 = kb + 3; }
    s = e20 - 2.f * a20; if (s < best2) { best2 = s; bi2 = kb; }
    s = e21 - 2.f * a21; if (s < best2) { best2 = s; bi2 = kb + 1; }
    s = e22 - 2.f * a22; if (s < best2) { best2 = s; bi2 = kb + 2; }
    s = e23 - 2.f * a23; if (s < best2) { best2 = s; bi2 = kb + 3; }
    s = e20 - 2.f * a30; if (s < best3) { best3 = s; bi3 = kb; }
    s = e21 - 2.f * a31; if (s < best3) { best3 = s; bi3 = kb + 1; }
    s = e22 - 2.f * a32; if (s < best3) { best3 = s; bi3 = kb + 2; }
    s = e23 - 2.f * a33; if (s < best3) { best3 = s; bi3 = kb + 3; }
  }
  __syncthreads();
  const int prow = pg << 2;
  red_d[(prow + 0) * 16 + kg] = best0; red_i[(prow + 0) * 16 + kg] = bi0;
  red_d[(prow + 1) * 16 + kg] = best1; red_i[(prow + 1) * 16 + kg] = bi1;
  red_d[(prow + 2) * 16 + kg] = best2; red_i[(prow + 2) * 16 + kg] = bi2;
  red_d[(prow + 3) * 16 + kg] = best3; red_i[(prow + 3) * 16 + kg] = bi3;
  __syncthreads();
  if (t < 64) {
    float bd = red_d[t * 16];
    int bk = red_i[t * 16];
    for (int g = 1; g < 16; ++g) {
      float d = red_d[t * 16 + g];
      int k = red_i[t * 16 + g];
      if (d < bd || (d == bd && k < bk)) { bd = d; bk = k; }
    }
    bidx_s[t] = bk;
  }
  __syncthreads();
  float lsum = 0.f;
  float* outb = out + (size_t)b * C_DIM * HW + p0;
#pragma unroll 4
  for (int i = 0; i < 16; ++i) {
    int fidx = t + 256 * i;
    int c = fidx >> 4, p4 = (fidx & 15) << 2;
    const float4 x4 = *(const float4*)&xb[(size_t)c * HW + p4];
    const int j0 = bidx_s[p4], j1 = bidx_s[p4 + 1], j2 = bidx_s[p4 + 2], j3 = bidx_s[p4 + 3];
    const float q0 = emb[(size_t)j0 * C_DIM + c];
    const float q1 = emb[(size_t)j1 * C_DIM + c];
    const float q2 = emb[(size_t)j2 * C_DIM + c];
    const float q3 = emb[(size_t)j3 * C_DIM + c];
    const float d0 = q0 - x4.x, d1 = q1 - x4.y, d2 = q2 - x4.z, d3 = q3 - x4.w;
    lsum += d0 * d0 + d1 * d1 + d2 * d2 + d3 * d3;
    float4 o; o.x = q0; o.y = q1; o.z = q2; o.w = q3;
    *(float4*)&outb[(size_t)c * HW + p4] = o;
  }
  for (int off = 32; off > 0; off >>= 1) lsum += __shfl_down(lsum, off, 64);
  if ((t & 63) == 0) lred[t >> 6] = lsum;
  __syncthreads();
  if (t == 0) atomicAdd(loss_acc, lred[0] + lred[1] + lred[2] + lred[3]);
}

// ============================================================================
extern "C" void kernel_launch(void* const* d_in, const int* in_sizes, int n_in,
                              void* d_out, int out_size, void* d_ws, size_t ws_size,
                              hipStream_t stream) {
  const float* x = (const float*)d_in[0];
  const float* emb = (const float*)d_in[1];
  float* out = (float*)d_out;
  char* ws = (char*)d_ws;

  // ws: 0 loss | 4 cnt | 256 e2 (4 KB) | 8192 idx (256 KB)
  //     | 270336 list (256 KB) | 532480 Bp (512 KB)
  //     | 1056768 d1o (512 KB) | 1581056 d2o (512 KB) | 2105344 i1o (512 KB)
  //     | end 2629632
  const size_t NEED = 2629632;
  if (ws_size >= NEED) {
    float* lossp = (float*)ws;
    int* cntp = (int*)(ws + 4);
    float* e2 = (float*)(ws + 256);
    int* idx = (int*)(ws + 8192);
    int* list = (int*)(ws + 270336);
    unsigned* Bp = (unsigned*)(ws + 532480);
    float* d1o = (float*)(ws + 1056768);
    float* d2o = (float*)(ws + 1581056);
    int* i1o = (int*)(ws + 2105344);
    k_prep<<<385, 256, 0, stream>>>(emb, e2, Bp, lossp, cntp);
    k_main<<<1024, 256, 0, stream>>>(x, Bp, e2, d1o, d2o, i1o);
    k_merge<<<256, 256, 0, stream>>>(d1o, d2o, i1o, idx, list, cntp);
    k_recheck<<<RGRID, 256, 0, stream>>>(x, emb, e2, list, cntp, idx);
    k_epi<<<1024, 256, 0, stream>>>(x, emb, idx, out, lossp);
    k_final<<<1, 1, 0, stream>>>(lossp, out);
  } else {
    float* wsf = (float*)ws;
    float* e2 = wsf + 64;
    k_zero<<<1, 1, 0, stream>>>(wsf);
    k_e2f<<<K_CODES / 256, 256, 0, stream>>>(emb, e2);
    k_main_r1<<<1024, 256, 0, stream>>>(x, emb, e2, out, wsf);
    k_final<<<1, 1, 0, stream>>>(wsf, out);
  }
}

// Round 8
// 276.634 us; speedup vs baseline: 1.3365x; 1.3365x over previous
//
#include <hip/hip_runtime.h>
#include <hip/hip_fp16.h>

// VectorQuantizer — round 15: B-SIDE hi/lo split (register-budget fix).
// r13/r14 post-mortem: A-side hi/lo needs 128 frag regs + ~60 more ≈ 190;
// per-SIMD pool = 512 regs/lane -> mi=2+A-hi/lo caps at 2 waves/SIMD; any
// launch_bounds asking for more just spills (100-225 MB scratch WRITE).
// Fix: split e (not x): Bp stores eh=fp16(e) AND el=fp16(e-eh); A = fp16(x)
// single set (64 regs). score = e2 - 2[dot(xh,eh)+dot(xh,el)]; error =
// dot(x-fp16(x), e), sigma~4.6e-3, symmetric to A-side -> TAU=0.075 holds.
// Regs ~120 <= 128 -> TRUE 4 waves/SIMD at launch_bounds(256,4), no spill.
// Geometry: 1024 blocks = 2 code-halves x 512 px-stripes, wave=32px (mi=2),
// 16 passes x 32 codes (hi+lo = 32KB tile). LDS floor 41us, MFMA 33us,
// separate pipes at 16 waves/CU. k_merge combines halves (exact tie-break,
// verified r13/r14: absmax 0). 6 dispatches: prep,main,merge,recheck,epi,final.

#define C_DIM   256
#define K_CODES 1024
#define HW      4096
#define N_OUT   (16 * C_DIM * HW)
#define TAU     0.075f
#define LISTCAP 65536
#define RPP     8
#define RGRID   512

typedef _Float16 f16x8 __attribute__((ext_vector_type(8)));
typedef float    f32x4 __attribute__((ext_vector_type(4)));
typedef unsigned u32x4 __attribute__((ext_vector_type(4)));

__device__ __forceinline__ void gld16(const void* g, void* lds) {
#if __has_builtin(__builtin_amdgcn_global_load_lds)
  __builtin_amdgcn_global_load_lds(
      (const __attribute__((address_space(1))) unsigned int*)g,
      (__attribute__((address_space(3))) unsigned int*)lds, 16, 0, 0);
#else
  ((int4*)lds)[threadIdx.x & 63] = *(const int4*)g;
#endif
}

// ---- fused prep: blocks 0-255 pack Bp (hi+lo); 256-511 e2; 512 zeros -----
// Bp slot s in [0,65536): l=s&63, ks=(s>>6)&7, set=(s>>9)&1, ni=(s>>10)&1,
// pp=s>>11 in [0,32) (pass-unit: h=pp>>4, p=pp&15).
// code n = pp*32 + ni*16 + (l&15); c0 = ks*32 + (l>>4)*8; 4 dw = 8 consec c.
// set 0 = eh = fp16(e); set 1 = el = fp16(e - float(eh)).
__global__ __launch_bounds__(256) void k_prep(const float* __restrict__ emb,
                                              float* __restrict__ e2,
                                              unsigned* __restrict__ Bp,
                                              float* __restrict__ lossp,
                                              int* __restrict__ cntp) {
  const int blk = blockIdx.x, t = threadIdx.x;
  if (blk < 256) {
    const int s = blk * 256 + t;
    const int l = s & 63, ks = (s >> 6) & 7, set = (s >> 9) & 1;
    const int ni = (s >> 10) & 1, pp = s >> 11;
    const int n = (pp << 5) + (ni << 4) + (l & 15);
    const int c0 = (ks << 5) + ((l >> 4) << 3);
    const float* er = emb + (size_t)n * C_DIM + c0;
    u32x4 out;
#pragma unroll
    for (int d = 0; d < 4; ++d) {
      const float v0 = er[2 * d], v1 = er[2 * d + 1];
      __half2 h = __floats2half2_rn(v0, v1);
      if (set) {
        __half2 hl = __floats2half2_rn(v0 - __low2float(h), v1 - __high2float(h));
        out[d] = *(unsigned*)&hl;
      } else {
        out[d] = *(unsigned*)&h;
      }
    }
    *(u32x4*)(Bp + (size_t)s * 4) = out;
  } else if (blk < 512) {
    const int w = t >> 6, l = t & 63;
    const int k = (blk - 256) * 4 + w;
    const float4 v = *(const float4*)(emb + (size_t)k * C_DIM + l * 4);
    float s = v.x * v.x + v.y * v.y + v.z * v.z + v.w * v.w;
    for (int m = 32; m; m >>= 1) s += __shfl_down(s, m, 64);
    if (l == 0) e2[k] = s;
  } else if (t == 0) {
    *lossp = 0.f; *cntp = 0;
  }
}

// ---- main: 1024 blocks = 2 code-halves x 512 px-stripes; mi=2, B hi/lo ----
__global__ __launch_bounds__(256, 4) void k_main(
    const float* __restrict__ x, const unsigned* __restrict__ Bp,
    const float* __restrict__ e2g, float* __restrict__ d1o,
    float* __restrict__ d2o, int* __restrict__ i1o) {
  __shared__ unsigned Bs[32 * 256];   // 32 KB: 32 codes/pass (hi+lo sets)
  __shared__ float e2s[512];          // 2 KB   (total 34 KB -> 4 blocks/CU)

  const int t = threadIdx.x;
  const int wv = t >> 6, l = t & 63;
  const int l15 = l & 15, l4 = l >> 4;
  const int blk = blockIdx.x;         // 1024 = 2 halves * (16 b * 32 stripes)
  const int h = blk >> 9;             // code half 0/1
  const int s = blk & 511;
  const int b = s >> 5;
  const int p0 = (s & 31) << 7;       // 128-px stripe
  const int pxw = p0 + (wv << 5);     // wave's 32-px base (2 mi)
  const float* xb = x + ((size_t)b << 20);

  e2s[t] = e2g[(h << 9) + t];
  e2s[t + 256] = e2g[(h << 9) + 256 + t];

  // A fragments: single fp16(x) set, 2 mi x 8 ks = 64 regs
  u32x4 afu[2][8];
#pragma unroll
  for (int mi = 0; mi < 2; ++mi) {
    const int px = pxw + (mi << 4) + l15;
#pragma unroll
    for (int ks = 0; ks < 8; ++ks) {
#pragma unroll
      for (int d = 0; d < 4; ++d) {
        const int c = (ks << 5) + (l4 << 3) + (d << 1);
        const float v0 = xb[((size_t)c << 12) + px];
        const float v1 = xb[((size_t)(c + 1) << 12) + px];
        __half2 hh = __floats2half2_rn(v0, v1);
        afu[mi][ks][d] = *(unsigned*)&hh;
      }
    }
  }

  float d1[2][4], d2v[2][4];
  int   i1[2][4];
#pragma unroll
  for (int mi = 0; mi < 2; ++mi)
#pragma unroll
    for (int r = 0; r < 4; ++r) { d1[mi][r] = 1e30f; d2v[mi][r] = 1e30f; i1[mi][r] = 0; }

  const unsigned* bph = Bp + ((size_t)(h << 4) << 13);  // this half's 16 passes
  for (int p = 0; p < 16; ++p) {      // 16 passes x 32 codes = 512 codes
    __syncthreads();                  // prev-pass consumers done
    const unsigned* src = bph + ((size_t)p << 13);      // 8192 dw per pass
#pragma unroll
    for (int i = 0; i < 8; ++i) {
      const int lt = (wv << 3) + i;   // local tile = ni*16+set*8+ks in [0,32)
      gld16(src + (lt << 8) + (l << 2), (void*)&Bs[lt << 8]);
    }
    __syncthreads();                  // staged data visible

    f32x4 acc[2][2];
#pragma unroll
    for (int mi = 0; mi < 2; ++mi)
#pragma unroll
      for (int ni = 0; ni < 2; ++ni) acc[mi][ni] = (f32x4){0.f, 0.f, 0.f, 0.f};

#pragma unroll
    for (int ni = 0; ni < 2; ++ni) {
#pragma unroll
      for (int ks = 0; ks < 8; ++ks) {
        const f16x8 a0 = __builtin_bit_cast(f16x8, afu[0][ks]);
        const f16x8 a1 = __builtin_bit_cast(f16x8, afu[1][ks]);
        const f16x8 bh = __builtin_bit_cast(
            f16x8, *(const u32x4*)&Bs[(((ni << 4) + ks) << 8) + (l << 2)]);
        const f16x8 bl = __builtin_bit_cast(
            f16x8, *(const u32x4*)&Bs[(((ni << 4) + 8 + ks) << 8) + (l << 2)]);
        // 2 ds_read feed 4 MFMA; acc sums dot(xh,eh)+dot(xh,el) = dot(xh,e)
        acc[0][ni] = __builtin_amdgcn_mfma_f32_16x16x32_f16(a0, bh, acc[0][ni], 0, 0, 0);
        acc[1][ni] = __builtin_amdgcn_mfma_f32_16x16x32_f16(a1, bh, acc[1][ni], 0, 0, 0);
        acc[0][ni] = __builtin_amdgcn_mfma_f32_16x16x32_f16(a0, bl, acc[0][ni], 0, 0, 0);
        acc[1][ni] = __builtin_amdgcn_mfma_f32_16x16x32_f16(a1, bl, acc[1][ni], 0, 0, 0);
      }
    }

    // register top-2 update over this half's local code ids [0,512)
    const int p32 = p << 5;
#pragma unroll
    for (int ni = 0; ni < 2; ++ni) {
      const int   c   = p32 + (ni << 4) + l15;
      const float e2v = e2s[c];
#pragma unroll
      for (int mi = 0; mi < 2; ++mi)
#pragma unroll
        for (int r = 0; r < 4; ++r) {
          const float sc = fmaf(-2.f, acc[mi][ni][r], e2v);
          const bool lt = sc < d1[mi][r];
          d2v[mi][r] = lt ? d1[mi][r] : (sc < d2v[mi][r] ? sc : d2v[mi][r]);
          i1[mi][r]  = lt ? c : i1[mi][r];
          d1[mi][r]  = lt ? sc : d1[mi][r];
        }
    }
  }

  // cross-lane merge (16 lanes share a pixel row); write half-results
#pragma unroll
  for (int mi = 0; mi < 2; ++mi) {
#pragma unroll
    for (int r = 0; r < 4; ++r) {
      float pd1 = d1[mi][r], pd2 = d2v[mi][r];
      int   pi1 = i1[mi][r];
#pragma unroll
      for (int m = 1; m < 16; m <<= 1) {
        const float od1 = __shfl_xor(pd1, m);
        const float od2 = __shfl_xor(pd2, m);
        const int   oi1 = __shfl_xor(pi1, m);
        const bool take = (od1 < pd1) || (od1 == pd1 && oi1 < pi1);
        const float loser = take ? pd1 : od1;
        pd2 = fminf(fminf(pd2, od2), loser);
        pd1 = take ? od1 : pd1;
        pi1 = take ? oi1 : pi1;
      }
      if (l15 == 0) {
        const int px = pxw + (mi << 4) + (l4 << 2) + r;
        const int gp = (b << 12) + px;
        const int off = (h << 16) + gp;
        d1o[off] = pd1;
        d2o[off] = pd2;
        i1o[off] = (h << 9) + pi1;    // global code index
      }
    }
  }
}

// ---- merge: per-px top-2 across the two code halves; flag near-ties -------
__global__ __launch_bounds__(256) void k_merge(
    const float* __restrict__ d1o, const float* __restrict__ d2o,
    const int* __restrict__ i1o, int* __restrict__ idxw,
    int* __restrict__ list, int* __restrict__ cntp) {
  const int px = blockIdx.x * 256 + threadIdx.x;   // 256 blocks
  const float a1 = d1o[px], a2 = d2o[px];
  const int   ai = i1o[px];
  const float b1 = d1o[65536 + px], b2 = d2o[65536 + px];
  const int   bi = i1o[65536 + px];
  // exact sequential tie-break: lower index wins on equal d1 (ai < bi always)
  const bool take_a = (a1 < b1) || (a1 == b1 && ai < bi);
  const float d1 = take_a ? a1 : b1;
  const int   i1 = take_a ? ai : bi;
  const float loser = take_a ? b1 : a1;
  const float d2 = fminf(fminf(a2, b2), loser);
  idxw[px] = i1;
  if (d2 - d1 < TAU) {
    const int pos = atomicAdd(cntp, 1);
    if (pos < LISTCAP) list[pos] = px;
  }
}

// ---- exact fp32 recheck: 8 flagged pixels per block share codebook sweep --
__global__ __launch_bounds__(256) void k_recheck(
    const float* __restrict__ x, const float* __restrict__ emb,
    const float* __restrict__ e2, const int* __restrict__ list,
    const int* __restrict__ cntp, int* __restrict__ idxw) {
  __shared__ float xs[RPP][C_DIM];
  __shared__ int   gps[RPP];
  __shared__ float wbest[RPP][4];
  __shared__ int   wbidx[RPP][4];
  const int t = threadIdx.x;
  const int cnt = min(*cntp, LISTCAP);
  float e2l[4];
#pragma unroll
  for (int j = 0; j < 4; ++j) e2l[j] = e2[t * 4 + j];

  for (int base = blockIdx.x * RPP; base < cnt; base += RGRID * RPP) {
    __syncthreads();
    if (t < RPP) gps[t] = (base + t < cnt) ? list[base + t] : -1;
    __syncthreads();
#pragma unroll
    for (int s = 0; s < RPP; ++s) {
      const int gp = gps[s];
      if (gp >= 0)
        xs[s][t] = x[((size_t)(gp >> 12) << 20) + ((size_t)t << 12) + (gp & 4095)];
    }
    __syncthreads();

    float acc[4][RPP];
#pragma unroll
    for (int j = 0; j < 4; ++j)
#pragma unroll
      for (int s = 0; s < RPP; ++s) acc[j][s] = 0.f;

    const float* er = emb + (size_t)(t * 4) * C_DIM;
    for (int c = 0; c < C_DIM; c += 4) {
      const float4 e0 = *(const float4*)(er + c);
      const float4 e1 = *(const float4*)(er + C_DIM + c);
      const float4 e2r = *(const float4*)(er + 2 * C_DIM + c);
      const float4 e3 = *(const float4*)(er + 3 * C_DIM + c);
#pragma unroll
      for (int s = 0; s < RPP; ++s) {
        const float4 xv = *(const float4*)&xs[s][c];
        acc[0][s] = fmaf(e0.x, xv.x, acc[0][s]); acc[0][s] = fmaf(e0.y, xv.y, acc[0][s]);
        acc[0][s] = fmaf(e0.z, xv.z, acc[0][s]); acc[0][s] = fmaf(e0.w, xv.w, acc[0][s]);
        acc[1][s] = fmaf(e1.x, xv.x, acc[1][s]); acc[1][s] = fmaf(e1.y, xv.y, acc[1][s]);
        acc[1][s] = fmaf(e1.z, xv.z, acc[1][s]); acc[1][s] = fmaf(e1.w, xv.w, acc[1][s]);
        acc[2][s] = fmaf(e2r.x, xv.x, acc[2][s]); acc[2][s] = fmaf(e2r.y, xv.y, acc[2][s]);
        acc[2][s] = fmaf(e2r.z, xv.z, acc[2][s]); acc[2][s] = fmaf(e2r.w, xv.w, acc[2][s]);
        acc[3][s] = fmaf(e3.x, xv.x, acc[3][s]); acc[3][s] = fmaf(e3.y, xv.y, acc[3][s]);
        acc[3][s] = fmaf(e3.z, xv.z, acc[3][s]); acc[3][s] = fmaf(e3.w, xv.w, acc[3][s]);
      }
    }

    for (int s = 0; s < RPP; ++s) {
      float bd = 1e30f;
      int   bk = 0;
#pragma unroll
      for (int j = 0; j < 4; ++j) {
        const float sc = fmaf(-2.f, acc[j][s], e2l[j]);
        if (sc < bd) { bd = sc; bk = t * 4 + j; }   // ascending j => first idx
      }
#pragma unroll
      for (int m = 1; m < 64; m <<= 1) {
        const float od = __shfl_xor(bd, m);
        const int   oi = __shfl_xor(bk, m);
        if (od < bd || (od == bd && oi < bk)) { bd = od; bk = oi; }
      }
      if ((t & 63) == 0) { wbest[s][t >> 6] = bd; wbidx[s][t >> 6] = bk; }
    }
    __syncthreads();
    if (t < RPP && gps[t] >= 0) {
      float bd = wbest[t][0];
      int   bk = wbidx[t][0];
      for (int wv = 1; wv < 4; ++wv)
        if (wbest[t][wv] < bd || (wbest[t][wv] == bd && wbidx[t][wv] < bk)) {
          bd = wbest[t][wv]; bk = wbidx[t][wv];
        }
      idxw[gps[t]] = bk;
    }
  }
}

// ---- epilogue: gather + transposed store + loss (r1/r3-validated) ---------
__global__ __launch_bounds__(256) void k_epi(const float* __restrict__ x,
                                             const float* __restrict__ emb,
                                             const int* __restrict__ idxw,
                                             float* __restrict__ out,
                                             float* __restrict__ loss_acc) {
  __shared__ int bidx_s[64];
  __shared__ float lred[4];
  const int t = threadIdx.x;
  const int tile = blockIdx.x;     // 1024 = 16 b * 64
  const int b = tile >> 6, p0 = (tile & 63) << 6;
  const float* xb = x + ((size_t)b << 20) + p0;
  float* outb = out + ((size_t)b << 20) + p0;
  if (t < 64) bidx_s[t] = idxw[((size_t)b << 12) + p0 + t] & 1023;
  __syncthreads();
  float lsum = 0.f;
#pragma unroll 4
  for (int i = 0; i < 16; ++i) {
    const int fidx = t + 256 * i;
    const int c = fidx >> 4, p4 = (fidx & 15) << 2;
    const float4 x4 = *(const float4*)&xb[((size_t)c << 12) + p4];
    const int j0 = bidx_s[p4], j1 = bidx_s[p4 + 1], j2 = bidx_s[p4 + 2], j3 = bidx_s[p4 + 3];
    const float q0 = emb[(size_t)j0 * C_DIM + c];
    const float q1 = emb[(size_t)j1 * C_DIM + c];
    const float q2 = emb[(size_t)j2 * C_DIM + c];
    const float q3 = emb[(size_t)j3 * C_DIM + c];
    const float d0 = q0 - x4.x, dd1 = q1 - x4.y, dd2 = q2 - x4.z, dd3 = q3 - x4.w;
    lsum += d0 * d0 + dd1 * dd1 + dd2 * dd2 + dd3 * dd3;
    float4 o; o.x = q0; o.y = q1; o.z = q2; o.w = q3;
    *(float4*)&outb[((size_t)c << 12) + p4] = o;
  }
  for (int off = 32; off > 0; off >>= 1) lsum += __shfl_down(lsum, off, 64);
  if ((t & 63) == 0) lred[t >> 6] = lsum;
  __syncthreads();
  if (t == 0) atomicAdd(loss_acc, lred[0] + lred[1] + lred[2] + lred[3]);
}

__global__ void k_final(const float* __restrict__ ws, float* __restrict__ out) {
  out[N_OUT] = 2.0f * ws[0] / (float)N_OUT;
}

// ================= round-1 fp32 fallback (tiny ws) ==========================
__global__ void k_zero(float* ws) { ws[0] = 0.f; }

__global__ __launch_bounds__(256) void k_e2f(const float* __restrict__ emb,
                                             float* __restrict__ e2) {
  int k = blockIdx.x * 256 + threadIdx.x;
  const float* e = emb + (size_t)k * C_DIM;
  float s = 0.f;
#pragma unroll 8
  for (int c = 0; c < C_DIM; ++c) s += e[c] * e[c];
  e2[k] = s;
}

__global__ __launch_bounds__(256, 4) void k_main_r1(
    const float* __restrict__ x, const float* __restrict__ emb,
    const float* __restrict__ e2, float* __restrict__ out,
    float* __restrict__ loss_acc) {
  __shared__ float smem[64 * 64 + 64 * 64];
  float* xs = smem;
  float* es = smem + 64 * 64;
  float* red_d = smem;
  int* red_i = (int*)(smem + 64 * 16);
  int* bidx_s = (int*)(smem + 64 * 32);
  float* lred = smem + 64 * 32 + 64;
  const int t = threadIdx.x;
  const int tile = blockIdx.x;
  const int b = tile >> 6;
  const int p0 = (tile & 63) << 6;
  const float* xb = x + (size_t)b * C_DIM * HW + p0;
  const int pg = t & 15, kg = t >> 4;
  float best0 = 1e30f, best1 = 1e30f, best2 = 1e30f, best3 = 1e30f;
  int bi0 = 0, bi1 = 0, bi2 = 0, bi3 = 0;
  for (int kc = 0; kc < 16; ++kc) {
    const int k0 = kc * 64;
    float a00 = 0, a01 = 0, a02 = 0, a03 = 0, a10 = 0, a11 = 0, a12 = 0, a13 = 0;
    float a20 = 0, a21 = 0, a22 = 0, a23 = 0, a30 = 0, a31 = 0, a32 = 0, a33 = 0;
    for (int cs0 = 0; cs0 < 4; ++cs0) {
      __syncthreads();
#pragma unroll
      for (int i = 0; i < 4; ++i) {
        int fidx = t + 256 * i;
        int cs = fidx >> 4, p4 = (fidx & 15) << 2;
        *(float4*)&xs[cs * 64 + p4] = *(const float4*)&xb[(size_t)(cs0 * 64 + cs) * HW + p4];
      }
      for (int i = 0; i < 16; ++i) {
        int idx2 = t + 256 * i;
        int cs = idx2 >> 6, kk = idx2 & 63;
        es[cs * 64 + kk] = emb[(size_t)(k0 + kk) * C_DIM + cs0 * 64 + cs];
      }
      __syncthreads();
#pragma unroll 8
      for (int cs = 0; cs < 64; ++cs) {
        const float4 xv = *(const float4*)&xs[cs * 64 + (pg << 2)];
        const float4 ev = *(const float4*)&es[cs * 64 + (kg << 2)];
        a00 += xv.x * ev.x; a01 += xv.x * ev.y; a02 += xv.x * ev.z; a03 += xv.x * ev.w;
        a10 += xv.y * ev.x; a11 += xv.y * ev.y; a12 += xv.y * ev.z; a13 += xv.y * ev.w;
        a20 += xv.z * ev.x; a21 += xv.z * ev.y; a22 += xv.z * ev.z; a23 += xv.z * ev.w;
        a30 += xv.w * ev.x; a31 += xv.w * ev.y; a32 += xv.w * ev.z; a33 += xv.w * ev.w;
      }
    }
    const int kb = k0 + (kg << 2);
    const float e20 = e2[kb], e21 = e2[kb + 1], e22 = e2[kb + 2], e23 = e2[kb + 3];
    float s;
    s = e20 - 2.f * a00; if (s < best0) { best0 = s; bi0 = kb; }
    s = e21 - 2.f * a01; if (s < best0) { best0 = s; bi0 = kb + 1; }
    s = e22 - 2.f * a02; if (s < best0) { best0 = s; bi0 = kb + 2; }
    s = e23 - 2.f * a03; if (s < best0) { best0 = s; bi0 = kb + 3; }
    s = e20 - 2.f * a10; if (s < best1) { best1 = s; bi1 = kb; }
    s = e21 - 2.f * a11; if (s < best1) { best1 = s; bi1 = kb + 1; }
    s = e22 - 2.f * a12; if (s < best1) { best1 = s; bi1 = kb + 2; }
    s = e23 - 2.f * a13; if (s < best1) { best1 = s; bi1 = kb + 3; }
    s = e20 - 2.f * a20; if (s < best2) { best2 = s; bi2 = kb; }
    s = e21 - 2.f * a21; if (s < best2) { best2 = s; bi2 = kb + 1; }
    s = e22 - 2.f * a22; if (s < best2) { best2 = s; bi2 = kb + 2; }
    s = e23 - 2.f * a23; if (s < best2) { best2 = s; bi2 = kb + 3; }
    s = e20 - 2.f * a30; if (s < best3) { best3 = s; bi3 = kb; }
    s = e21 - 2.f * a31; if (s < best3) { best3 = s; bi3 = kb + 1; }
    s = e22 - 2.f * a32; if (s < best3) { best3 = s; bi3 = kb + 2; }
    s = e23 - 2.f * a33; if (s < best3) { best3 = s; bi3 = kb + 3; }
  }
  __syncthreads();
  const int prow = pg << 2;
  red_d[(prow + 0) * 16 + kg] = best0; red_i[(prow + 0) * 16 + kg] = bi0;
  red_d[(prow + 1) * 16 + kg] = best1; red_i[(prow + 1) * 16 + kg] = bi1;
  red_d[(prow + 2) * 16 + kg] = best2; red_i[(prow + 2) * 16 + kg] = bi2;
  red_d[(prow + 3) * 16 + kg] = best3; red_i[(prow + 3) * 16 + kg] = bi3;
  __syncthreads();
  if (t < 64) {
    float bd = red_d[t * 16];
    int bk = red_i[t * 16];
    for (int g = 1; g < 16; ++g) {
      float d = red_d[t * 16 + g];
      int k = red_i[t * 16 + g];
      if (d < bd || (d == bd && k < bk)) { bd = d; bk = k; }
    }
    bidx_s[t] = bk;
  }
  __syncthreads();
  float lsum = 0.f;
  float* outb = out + (size_t)b * C_DIM * HW + p0;
#pragma unroll 4
  for (int i = 0; i < 16; ++i) {
    int fidx = t + 256 * i;
    int c = fidx >> 4, p4 = (fidx & 15) << 2;
    const float4 x4 = *(const float4*)&xb[(size_t)c * HW + p4];
    const int j0 = bidx_s[p4], j1 = bidx_s[p4 + 1], j2 = bidx_s[p4 + 2], j3 = bidx_s[p4 + 3];
    const float q0 = emb[(size_t)j0 * C_DIM + c];
    const float q1 = emb[(size_t)j1 * C_DIM + c];
    const float q2 = emb[(size_t)j2 * C_DIM + c];
    const float q3 = emb[(size_t)j3 * C_DIM + c];
    const float d0 = q0 - x4.x, d1 = q1 - x4.y, d2 = q2 - x4.z, d3 = q3 - x4.w;
    lsum += d0 * d0 + d1 * d1 + d2 * d2 + d3 * d3;
    float4 o; o.x = q0; o.y = q1; o.z = q2; o.w = q3;
    *(float4*)&outb[(size_t)c * HW + p4] = o;
  }
  for (int off = 32; off > 0; off >>= 1) lsum += __shfl_down(lsum, off, 64);
  if ((t & 63) == 0) lred[t >> 6] = lsum;
  __syncthreads();
  if (t == 0) atomicAdd(loss_acc, lred[0] + lred[1] + lred[2] + lred[3]);
}

// ============================================================================
extern "C" void kernel_launch(void* const* d_in, const int* in_sizes, int n_in,
                              void* d_out, int out_size, void* d_ws, size_t ws_size,
                              hipStream_t stream) {
  const float* x = (const float*)d_in[0];
  const float* emb = (const float*)d_in[1];
  float* out = (float*)d_out;
  char* ws = (char*)d_ws;

  // ws: 0 loss | 4 cnt | 256 e2 (4 KB) | 8192 idx (256 KB)
  //     | 270336 list (256 KB) | 532480 Bp (1 MB)
  //     | 1581056 d1o (512 KB) | 2105344 d2o (512 KB) | 2629632 i1o (512 KB)
  //     | end 3153920
  const size_t NEED = 3153920;
  if (ws_size >= NEED) {
    float* lossp = (float*)ws;
    int* cntp = (int*)(ws + 4);
    float* e2 = (float*)(ws + 256);
    int* idx = (int*)(ws + 8192);
    int* list = (int*)(ws + 270336);
    unsigned* Bp = (unsigned*)(ws + 532480);
    float* d1o = (float*)(ws + 1581056);
    float* d2o = (float*)(ws + 2105344);
    int* i1o = (int*)(ws + 2629632);
    k_prep<<<513, 256, 0, stream>>>(emb, e2, Bp, lossp, cntp);
    k_main<<<1024, 256, 0, stream>>>(x, Bp, e2, d1o, d2o, i1o);
    k_merge<<<256, 256, 0, stream>>>(d1o, d2o, i1o, idx, list, cntp);
    k_recheck<<<RGRID, 256, 0, stream>>>(x, emb, e2, list, cntp, idx);
    k_epi<<<1024, 256, 0, stream>>>(x, emb, idx, out, lossp);
    k_final<<<1, 1, 0, stream>>>(lossp, out);
  } else {
    float* wsf = (float*)ws;
    float* e2 = wsf + 64;
    k_zero<<<1, 1, 0, stream>>>(wsf);
    k_e2f<<<K_CODES / 256, 256, 0, stream>>>(emb, e2);
    k_main_r1<<<1024, 256, 0, stream>>>(x, emb, e2, out, wsf);
    k_final<<<1, 1, 0, stream>>>(wsf, out);
  }
}

// Round 9
// 239.739 us; speedup vs baseline: 1.5421x; 1.1539x over previous
//
#include <hip/hip_runtime.h>
#include <hip/hip_fp16.h>

// VectorQuantizer — round 16: revert k_main to best-measured (r10) + attack
// the ~170us fixed cost outside k_main.
// r15 post-mortem: B-side hi/lo doubled LDS stream (41us floor) + doubled
// x-fetch; code-split line (r13-15) all <= baseline -> reverted.
// Fixed-cost model: k_recheck wall = ONE VALU-bound sweep (~27us; TAU can't
// reduce below 1 sweep) -> RPP 8->4, RGRID 1024 halves per-wave work (~14us).
// k_epi was gather-bound (64 scalar L2 gathers/thread ~27us + 21us HBM) ->
// rewritten: stage 32 emb rows into LDS (coalesced row reads, XOR-swizzled
// float4 slots cg^((px>>2)&7) — conflict-free in both phases), emit
// transposed out-tile from LDS (~25us). k_main arithmetic unchanged
// (A-side fp16 hi+lo, TAU=0.075, proven absmax 0).
// 5 dispatches: k_prep, k_main, k_recheck, k_epi, k_final.

#define C_DIM   256
#define K_CODES 1024
#define HW      4096
#define N_OUT   (16 * C_DIM * HW)
#define TAU     0.075f
#define LISTCAP 65536
#define RPP     4
#define RGRID   1024
#define EPP     32

typedef _Float16 f16x8 __attribute__((ext_vector_type(8)));
typedef float    f32x4 __attribute__((ext_vector_type(4)));
typedef unsigned u32x4 __attribute__((ext_vector_type(4)));

__device__ __forceinline__ void gld16(const void* g, void* lds) {
#if __has_builtin(__builtin_amdgcn_global_load_lds)
  __builtin_amdgcn_global_load_lds(
      (const __attribute__((address_space(1))) unsigned int*)g,
      (__attribute__((address_space(3))) unsigned int*)lds, 16, 0, 0);
#else
  ((int4*)lds)[threadIdx.x & 63] = *(const int4*)g;
#endif
}

// ---- fused prep: blocks 0-127 pack Bp; 128-383 e2; 384 zeros loss+cnt -----
// Bp slot s: l=s&63, ks=(s>>6)&7, ni=(s>>9)&7, cb=s>>12  (8 cb x 128 codes)
// code n = cb*128 + ni*16 + (l&15); c0 = ks*32 + (l>>4)*8; 4 dw = 8 consec. c
__global__ __launch_bounds__(256) void k_prep(const float* __restrict__ emb,
                                              float* __restrict__ e2,
                                              unsigned* __restrict__ Bp,
                                              float* __restrict__ lossp,
                                              int* __restrict__ cntp) {
  const int blk = blockIdx.x, t = threadIdx.x;
  if (blk < 128) {
    const int s = blk * 256 + t;
    const int l = s & 63, ks = (s >> 6) & 7, ni = (s >> 9) & 7, cb = s >> 12;
    const int n = (cb << 7) + (ni << 4) + (l & 15);
    const int c0 = (ks << 5) + ((l >> 4) << 3);
    const float* er = emb + (size_t)n * C_DIM + c0;
    u32x4 out;
#pragma unroll
    for (int d = 0; d < 4; ++d) {
      __half2 h = __floats2half2_rn(er[2 * d], er[2 * d + 1]);
      out[d] = *(unsigned*)&h;
    }
    *(u32x4*)(Bp + (size_t)s * 4) = out;
  } else if (blk < 384) {
    const int w = t >> 6, l = t & 63;
    const int k = (blk - 128) * 4 + w;
    const float4 v = *(const float4*)(emb + (size_t)k * C_DIM + l * 4);
    float s = v.x * v.x + v.y * v.y + v.z * v.z + v.w * v.w;
    for (int m = 32; m; m >>= 1) s += __shfl_down(s, m, 64);
    if (l == 0) e2[k] = s;
  } else if (t == 0) {
    *lossp = 0.f; *cntp = 0;
  }
}

// ---- main: r10 exact — 1024 blocks x 64-px stripes, mi=1, 4 blk/CU --------
__global__ __launch_bounds__(256, 4) void k_main(
    const float* __restrict__ x, const unsigned* __restrict__ Bp,
    const float* __restrict__ e2g, int* __restrict__ idxw,
    int* __restrict__ list, int* __restrict__ cntp) {
  __shared__ unsigned Bs[32 * 256];   // 32 KB single buffer: 64 codes/pass
  __shared__ float e2s[K_CODES];      // 4 KB  (total 36 KB -> 4 blocks/CU)

  const int t = threadIdx.x;
  const int wv = t >> 6, l = t & 63;
  const int l15 = l & 15, l4 = l >> 4;
  const int blk = blockIdx.x;         // 1024 = 16 b * 64 stripes
  const int b = blk >> 6;
  const int p0 = (blk & 63) << 6;     // 64-px stripe
  const int pxw = p0 + (wv << 4);     // wave's 16-px base (1 mi)
  const float* xb = x + ((size_t)b << 20);

#pragma unroll
  for (int i = 0; i < 4; ++i) e2s[t + 256 * i] = e2g[t + 256 * i];

  // A fragments: 1 mi x 8 ks, hi + residual-lo, converted once
  u32x4 afu[8];
  u32x4 afl[8];
  {
    const int px = pxw + l15;
#pragma unroll
    for (int ks = 0; ks < 8; ++ks) {
#pragma unroll
      for (int d = 0; d < 4; ++d) {
        const int c = (ks << 5) + (l4 << 3) + (d << 1);
        const float v0 = xb[((size_t)c << 12) + px];
        const float v1 = xb[((size_t)(c + 1) << 12) + px];
        __half2 h = __floats2half2_rn(v0, v1);
        afu[ks][d] = *(unsigned*)&h;
        __half2 hl = __floats2half2_rn(v0 - __low2float(h), v1 - __high2float(h));
        afl[ks][d] = *(unsigned*)&hl;
      }
    }
  }

  float d1[4], d2v[4];
  int   i1[4];
#pragma unroll
  for (int r = 0; r < 4; ++r) { d1[r] = 1e30f; d2v[r] = 1e30f; i1[r] = 0; }

  for (int p = 0; p < 16; ++p) {
    __syncthreads();                  // prev-pass consumers done
    const unsigned* src = Bp + ((size_t)(p >> 1) << 14) + ((p & 1) << 13);
#pragma unroll
    for (int i = 0; i < 8; ++i) {
      const int lt = (wv << 3) + i;   // local tile = ni*8+ks in [0,32)
      gld16(src + (lt << 8) + (l << 2), (void*)&Bs[lt << 8]);
    }
    __syncthreads();                  // implicit vmcnt(0): staged data visible

    f32x4 acc[4];
#pragma unroll
    for (int ni = 0; ni < 4; ++ni) acc[ni] = (f32x4){0.f, 0.f, 0.f, 0.f};

#pragma unroll
    for (int ks = 0; ks < 8; ++ks) {
      const f16x8 ah = __builtin_bit_cast(f16x8, afu[ks]);
      const f16x8 al = __builtin_bit_cast(f16x8, afl[ks]);
#pragma unroll
      for (int ni = 0; ni < 4; ++ni) {
        const f16x8 bf = __builtin_bit_cast(
            f16x8, *(const u32x4*)&Bs[(((ni << 3) + ks) << 8) + (l << 2)]);
        acc[ni] = __builtin_amdgcn_mfma_f32_16x16x32_f16(ah, bf, acc[ni], 0, 0, 0);
        acc[ni] = __builtin_amdgcn_mfma_f32_16x16x32_f16(al, bf, acc[ni], 0, 0, 0);
      }
    }

    // register top-2 update (merge deferred to kernel end)
    const int p64 = p << 6;
#pragma unroll
    for (int ni = 0; ni < 4; ++ni) {
      const int   c   = p64 + (ni << 4) + l15;
      const float e2v = e2s[c];
#pragma unroll
      for (int r = 0; r < 4; ++r) {
        const float s = fmaf(-2.f, acc[ni][r], e2v);
        const bool lt = s < d1[r];
        d2v[r] = lt ? d1[r] : (s < d2v[r] ? s : d2v[r]);
        i1[r]  = lt ? c : i1[r];
        d1[r]  = lt ? s : d1[r];
      }
    }
  }

  // single cross-lane merge (xor masks flip l15 — 16 lanes share a pixel row)
#pragma unroll
  for (int r = 0; r < 4; ++r) {
    float pd1 = d1[r], pd2 = d2v[r];
    int   pi1 = i1[r];
#pragma unroll
    for (int m = 1; m < 16; m <<= 1) {
      const float od1 = __shfl_xor(pd1, m);
      const float od2 = __shfl_xor(pd2, m);
      const int   oi1 = __shfl_xor(pi1, m);
      const bool take = (od1 < pd1) || (od1 == pd1 && oi1 < pi1);
      const float loser = take ? pd1 : od1;
      pd2 = fminf(fminf(pd2, od2), loser);
      pd1 = take ? od1 : pd1;
      pi1 = take ? oi1 : pi1;
    }
    if (l15 == 0) {
      const int px = pxw + (l4 << 2) + r;
      const int gp = (b << 12) + px;
      idxw[gp] = pi1;
      if (pd2 - pd1 < TAU) {
        const int pos = atomicAdd(cntp, 1);
        if (pos < LISTCAP) list[pos] = gp;
      }
    }
  }
}

// ---- exact fp32 recheck: RPP=4 px/block (halved per-wave sweep work) ------
__global__ __launch_bounds__(256) void k_recheck(
    const float* __restrict__ x, const float* __restrict__ emb,
    const float* __restrict__ e2, const int* __restrict__ list,
    const int* __restrict__ cntp, int* __restrict__ idxw) {
  __shared__ float xs[RPP][C_DIM];
  __shared__ int   gps[RPP];
  __shared__ float wbest[RPP][4];
  __shared__ int   wbidx[RPP][4];
  const int t = threadIdx.x;
  const int cnt = min(*cntp, LISTCAP);
  float e2l[4];
#pragma unroll
  for (int j = 0; j < 4; ++j) e2l[j] = e2[t * 4 + j];

  for (int base = blockIdx.x * RPP; base < cnt; base += RGRID * RPP) {
    __syncthreads();
    if (t < RPP) gps[t] = (base + t < cnt) ? list[base + t] : -1;
    __syncthreads();
#pragma unroll
    for (int s = 0; s < RPP; ++s) {
      const int gp = gps[s];
      if (gp >= 0)
        xs[s][t] = x[((size_t)(gp >> 12) << 20) + ((size_t)t << 12) + (gp & 4095)];
    }
    __syncthreads();

    float acc[4][RPP];
#pragma unroll
    for (int j = 0; j < 4; ++j)
#pragma unroll
      for (int s = 0; s < RPP; ++s) acc[j][s] = 0.f;

    const float* er = emb + (size_t)(t * 4) * C_DIM;
    for (int c = 0; c < C_DIM; c += 4) {
      const float4 e0 = *(const float4*)(er + c);
      const float4 e1 = *(const float4*)(er + C_DIM + c);
      const float4 e2r = *(const float4*)(er + 2 * C_DIM + c);
      const float4 e3 = *(const float4*)(er + 3 * C_DIM + c);
#pragma unroll
      for (int s = 0; s < RPP; ++s) {
        const float4 xv = *(const float4*)&xs[s][c];
        acc[0][s] = fmaf(e0.x, xv.x, acc[0][s]); acc[0][s] = fmaf(e0.y, xv.y, acc[0][s]);
        acc[0][s] = fmaf(e0.z, xv.z, acc[0][s]); acc[0][s] = fmaf(e0.w, xv.w, acc[0][s]);
        acc[1][s] = fmaf(e1.x, xv.x, acc[1][s]); acc[1][s] = fmaf(e1.y, xv.y, acc[1][s]);
        acc[1][s] = fmaf(e1.z, xv.z, acc[1][s]); acc[1][s] = fmaf(e1.w, xv.w, acc[1][s]);
        acc[2][s] = fmaf(e2r.x, xv.x, acc[2][s]); acc[2][s] = fmaf(e2r.y, xv.y, acc[2][s]);
        acc[2][s] = fmaf(e2r.z, xv.z, acc[2][s]); acc[2][s] = fmaf(e2r.w, xv.w, acc[2][s]);
        acc[3][s] = fmaf(e3.x, xv.x, acc[3][s]); acc[3][s] = fmaf(e3.y, xv.y, acc[3][s]);
        acc[3][s] = fmaf(e3.z, xv.z, acc[3][s]); acc[3][s] = fmaf(e3.w, xv.w, acc[3][s]);
      }
    }

    for (int s = 0; s < RPP; ++s) {
      float bd = 1e30f;
      int   bk = 0;
#pragma unroll
      for (int j = 0; j < 4; ++j) {
        const float sc = fmaf(-2.f, acc[j][s], e2l[j]);
        if (sc < bd) { bd = sc; bk = t * 4 + j; }   // ascending j => first idx
      }
#pragma unroll
      for (int m = 1; m < 64; m <<= 1) {
        const float od = __shfl_xor(bd, m);
        const int   oi = __shfl_xor(bk, m);
        if (od < bd || (od == bd && oi < bk)) { bd = od; bk = oi; }
      }
      if ((t & 63) == 0) { wbest[s][t >> 6] = bd; wbidx[s][t >> 6] = bk; }
    }
    __syncthreads();
    if (t < RPP && gps[t] >= 0) {
      float bd = wbest[t][0];
      int   bk = wbidx[t][0];
      for (int wv = 1; wv < 4; ++wv)
        if (wbest[t][wv] < bd || (wbest[t][wv] == bd && wbidx[t][wv] < bk)) {
          bd = wbest[t][wv]; bk = wbidx[t][wv];
        }
      idxw[gps[t]] = bk;
    }
  }
}

// ---- epilogue: LDS-staged emb rows (no global gathers) + transposed store -
// Block = 32 px x 256 c. Phase A: each wave reads one emb row coalesced
// (1 KB) and writes XOR-swizzled float4 slots. Phase B: read 4 px x 1 c per
// thread from LDS (swizzle gives distinct banks), fused loss, float4 store.
__global__ __launch_bounds__(256) void k_epi(const float* __restrict__ x,
                                             const float* __restrict__ emb,
                                             const int* __restrict__ idxw,
                                             float* __restrict__ out,
                                             float* __restrict__ loss_acc) {
  __shared__ float qs[EPP * C_DIM];   // 32 KB, swizzled float4 slots
  __shared__ int bidx_s[EPP];
  __shared__ float lred[4];
  const int t = threadIdx.x;
  const int tile = blockIdx.x;        // 2048 = 16 b * 128 tiles
  const int b = tile >> 7, p0 = (tile & 127) << 5;
  const float* xb = x + ((size_t)b << 20) + p0;
  float* outb = out + ((size_t)b << 20) + p0;
  if (t < EPP) bidx_s[t] = idxw[((size_t)b << 12) + p0 + t] & 1023;
  __syncthreads();
  // phase A: 32 rows x 64 float4 = 2048 slots; wave i stages row (idx>>6)
#pragma unroll
  for (int i = 0; i < 8; ++i) {
    const int idx2 = t + 256 * i;
    const int px = idx2 >> 6, cg = idx2 & 63;
    const float4 v = *(const float4*)(emb + (size_t)bidx_s[px] * C_DIM + (cg << 2));
    const int slot = (px << 6) + (cg ^ ((px >> 2) & 7));
    *(float4*)&qs[slot << 2] = v;
  }
  __syncthreads();
  float lsum = 0.f;
  // phase B: 32 px x 256 c / 4 px per thread = 8 iters
#pragma unroll
  for (int i = 0; i < 8; ++i) {
    const int fidx = t + 256 * i;
    const int c = fidx >> 3, p4 = (fidx & 7) << 2;
    const float4 x4 = *(const float4*)&xb[((size_t)c << 12) + p4];
    const int cg = c >> 2, cl = c & 3;
    float q[4];
#pragma unroll
    for (int k = 0; k < 4; ++k) {
      const int px = p4 + k;
      q[k] = qs[(((px << 6) + (cg ^ ((px >> 2) & 7))) << 2) + cl];
    }
    const float d0 = q[0] - x4.x, d1 = q[1] - x4.y;
    const float d2 = q[2] - x4.z, d3 = q[3] - x4.w;
    lsum += d0 * d0 + d1 * d1 + d2 * d2 + d3 * d3;
    float4 o; o.x = q[0]; o.y = q[1]; o.z = q[2]; o.w = q[3];
    *(float4*)&outb[((size_t)c << 12) + p4] = o;
  }
  for (int off = 32; off > 0; off >>= 1) lsum += __shfl_down(lsum, off, 64);
  if ((t & 63) == 0) lred[t >> 6] = lsum;
  __syncthreads();
  if (t == 0) atomicAdd(loss_acc, lred[0] + lred[1] + lred[2] + lred[3]);
}

__global__ void k_final(const float* __restrict__ ws, float* __restrict__ out) {
  out[N_OUT] = 2.0f * ws[0] / (float)N_OUT;
}

// ================= round-1 fp32 fallback (tiny ws) ==========================
__global__ void k_zero(float* ws) { ws[0] = 0.f; }

__global__ __launch_bounds__(256) void k_e2f(const float* __restrict__ emb,
                                             float* __restrict__ e2) {
  int k = blockIdx.x * 256 + threadIdx.x;
  const float* e = emb + (size_t)k * C_DIM;
  float s = 0.f;
#pragma unroll 8
  for (int c = 0; c < C_DIM; ++c) s += e[c] * e[c];
  e2[k] = s;
}

__global__ __launch_bounds__(256, 4) void k_main_r1(
    const float* __restrict__ x, const float* __restrict__ emb,
    const float* __restrict__ e2, float* __restrict__ out,
    float* __restrict__ loss_acc) {
  __shared__ float smem[64 * 64 + 64 * 64];
  float* xs = smem;
  float* es = smem + 64 * 64;
  float* red_d = smem;
  int* red_i = (int*)(smem + 64 * 16);
  int* bidx_s = (int*)(smem + 64 * 32);
  float* lred = smem + 64 * 32 + 64;
  const int t = threadIdx.x;
  const int tile = blockIdx.x;
  const int b = tile >> 6;
  const int p0 = (tile & 63) << 6;
  const float* xb = x + (size_t)b * C_DIM * HW + p0;
  const int pg = t & 15, kg = t >> 4;
  float best0 = 1e30f, best1 = 1e30f, best2 = 1e30f, best3 = 1e30f;
  int bi0 = 0, bi1 = 0, bi2 = 0, bi3 = 0;
  for (int kc = 0; kc < 16; ++kc) {
    const int k0 = kc * 64;
    float a00 = 0, a01 = 0, a02 = 0, a03 = 0, a10 = 0, a11 = 0, a12 = 0, a13 = 0;
    float a20 = 0, a21 = 0, a22 = 0, a23 = 0, a30 = 0, a31 = 0, a32 = 0, a33 = 0;
    for (int cs0 = 0; cs0 < 4; ++cs0) {
      __syncthreads();
#pragma unroll
      for (int i = 0; i < 4; ++i) {
        int fidx = t + 256 * i;
        int cs = fidx >> 4, p4 = (fidx & 15) << 2;
        *(float4*)&xs[cs * 64 + p4] = *(const float4*)&xb[(size_t)(cs0 * 64 + cs) * HW + p4];
      }
      for (int i = 0; i < 16; ++i) {
        int idx2 = t + 256 * i;
        int cs = idx2 >> 6, kk = idx2 & 63;
        es[cs * 64 + kk] = emb[(size_t)(k0 + kk) * C_DIM + cs0 * 64 + cs];
      }
      __syncthreads();
#pragma unroll 8
      for (int cs = 0; cs < 64; ++cs) {
        const float4 xv = *(const float4*)&xs[cs * 64 + (pg << 2)];
        const float4 ev = *(const float4*)&es[cs * 64 + (kg << 2)];
        a00 += xv.x * ev.x; a01 += xv.x * ev.y; a02 += xv.x * ev.z; a03 += xv.x * ev.w;
        a10 += xv.y * ev.x; a11 += xv.y * ev.y; a12 += xv.y * ev.z; a13 += xv.y * ev.w;
        a20 += xv.z * ev.x; a21 += xv.z * ev.y; a22 += xv.z * ev.z; a23 += xv.z * ev.w;
        a30 += xv.w * ev.x; a31 += xv.w * ev.y; a32 += xv.w * ev.z; a33 += xv.w * ev.w;
      }
    }
    const int kb = k0 + (kg << 2);
    const float e20 = e2[kb], e21 = e2[kb + 1], e22 = e2[kb + 2], e23 = e2[kb + 3];
    float s;
    s = e20 - 2.f * a00; if (s < best0) { best0 = s; bi0 = kb; }
    s = e21 - 2.f * a01; if (s < best0) { best0 = s; bi0 = kb + 1; }
    s = e22 - 2.f * a02; if (s < best0) { best0 = s; bi0 = kb + 2; }
    s = e23 - 2.f * a03; if (s < best0) { best0 = s; bi0 = kb + 3; }
    s = e20 - 2.f * a10; if (s < best1) { best1 = s; bi1 = kb; }
    s = e21 - 2.f * a11; if (s < best1) { best1 = s; bi1 = kb + 1; }
    s = e22 - 2.f * a12; if (s < best1) { best1 = s; bi1 = kb + 2; }
    s = e23 - 2.f * a13; if (s < best1) { best1 = s; bi1 = kb + 3; }
    s = e20 - 2.f * a20; if (s < best2) { best2 = s; bi2 = kb; }
    s = e21 - 2.f * a21; if (s < best2) { best2 = s; bi2 = kb + 1; }
    s = e22 - 2.f * a22; if (s < best2) { best2 = s; bi2 = kb + 2; }
    s = e23 - 2.f * a23; if (s < best2) { best2 = s; bi2 = kb + 3; }
    s = e20 - 2.f * a30; if (s < best3) { best3 = s; bi3 = kb; }
    s = e21 - 2.f * a31; if (s < best3) { best3 = s; bi3 = kb + 1; }
    s = e22 - 2.f * a32; if (s < best3) { best3 = s; bi3 = kb + 2; }
    s = e23 - 2.f * a33; if (s < best3) { best3 = s; bi3 = kb + 3; }
  }
  __syncthreads();
  const int prow = pg << 2;
  red_d[(prow + 0) * 16 + kg] = best0; red_i[(prow + 0) * 16 + kg] = bi0;
  red_d[(prow + 1) * 16 + kg] = best1; red_i[(prow + 1) * 16 + kg] = bi1;
  red_d[(prow + 2) * 16 + kg] = best2; red_i[(prow + 2) * 16 + kg] = bi2;
  red_d[(prow + 3) * 16 + kg] = best3; red_i[(prow + 3) * 16 + kg] = bi3;
  __syncthreads();
  if (t < 64) {
    float bd = red_d[t * 16];
    int bk = red_i[t * 16];
    for (int g = 1; g < 16; ++g) {
      float d = red_d[t * 16 + g];
      int k = red_i[t * 16 + g];
      if (d < bd || (d == bd && k < bk)) { bd = d; bk = k; }
    }
    bidx_s[t] = bk;
  }
  __syncthreads();
  float lsum = 0.f;
  float* outb = out + (size_t)b * C_DIM * HW + p0;
#pragma unroll 4
  for (int i = 0; i < 16; ++i) {
    int fidx = t + 256 * i;
    int c = fidx >> 4, p4 = (fidx & 15) << 2;
    const float4 x4 = *(const float4*)&xb[(size_t)c * HW + p4];
    const int j0 = bidx_s[p4], j1 = bidx_s[p4 + 1], j2 = bidx_s[p4 + 2], j3 = bidx_s[p4 + 3];
    const float q0 = emb[(size_t)j0 * C_DIM + c];
    const float q1 = emb[(size_t)j1 * C_DIM + c];
    const float q2 = emb[(size_t)j2 * C_DIM + c];
    const float q3 = emb[(size_t)j3 * C_DIM + c];
    const float d0 = q0 - x4.x, d1 = q1 - x4.y, d2 = q2 - x4.z, d3 = q3 - x4.w;
    lsum += d0 * d0 + d1 * d1 + d2 * d2 + d3 * d3;
    float4 o; o.x = q0; o.y = q1; o.z = q2; o.w = q3;
    *(float4*)&outb[(size_t)c * HW + p4] = o;
  }
  for (int off = 32; off > 0; off >>= 1) lsum += __shfl_down(lsum, off, 64);
  if ((t & 63) == 0) lred[t >> 6] = lsum;
  __syncthreads();
  if (t == 0) atomicAdd(loss_acc, lred[0] + lred[1] + lred[2] + lred[3]);
}

// ============================================================================
extern "C" void kernel_launch(void* const* d_in, const int* in_sizes, int n_in,
                              void* d_out, int out_size, void* d_ws, size_t ws_size,
                              hipStream_t stream) {
  const float* x = (const float*)d_in[0];
  const float* emb = (const float*)d_in[1];
  float* out = (float*)d_out;
  char* ws = (char*)d_ws;

  // ws: 0 loss | 4 cnt | 256 e2 (4 KB) | 8192 idx (256 KB)
  //     | 270336 list (256 KB) | 532480 Bp (512 KB) | end 1056768
  const size_t NEED = 1056768;
  if (ws_size >= NEED) {
    float* lossp = (float*)ws;
    int* cntp = (int*)(ws + 4);
    float* e2 = (float*)(ws + 256);
    int* idx = (int*)(ws + 8192);
    int* list = (int*)(ws + 270336);
    unsigned* Bp = (unsigned*)(ws + 532480);
    k_prep<<<385, 256, 0, stream>>>(emb, e2, Bp, lossp, cntp);
    k_main<<<1024, 256, 0, stream>>>(x, Bp, e2, idx, list, cntp);
    k_recheck<<<RGRID, 256, 0, stream>>>(x, emb, e2, list, cntp, idx);
    k_epi<<<2048, 256, 0, stream>>>(x, emb, idx, out, lossp);
    k_final<<<1, 1, 0, stream>>>(lossp, out);
  } else {
    float* wsf = (float*)ws;
    float* e2 = wsf + 64;
    k_zero<<<1, 1, 0, stream>>>(wsf);
    k_e2f<<<K_CODES / 256, 256, 0, stream>>>(emb, e2);
    k_main_r1<<<1024, 256, 0, stream>>>(x, emb, e2, out, wsf);
    k_final<<<1, 1, 0, stream>>>(wsf, out);
  }
}